// Round 6
// baseline (411.554 us; speedup 1.0000x reference)
//
#include <hip/hip_runtime.h>
#include <hip/hip_bf16.h>
#include <math.h>

// Shapes are fixed by the problem instance.
#define BDOCS   1024
#define CNODES  4096
#define INDIM   768
#define HID     512
#define NHEAD   4
#define HDIM    128
#define NEG_SLOPE 0.2f

typedef __attribute__((ext_vector_type(8))) short short8;   // 8 bf16 (4 VGPRs)
typedef __attribute__((ext_vector_type(4))) float f32x4;    // MFMA C/D

__device__ __forceinline__ float lrelu(float x) { return x > 0.f ? x : NEG_SLOPE * x; }

// float -> bf16 bits, round-to-nearest-even
__device__ __forceinline__ short f2bf(float f) {
    union { float f; unsigned u; } v; v.f = f;
    unsigned r = (v.u + 0x7fff + ((v.u >> 16) & 1)) >> 16;
    return (short)r;
}
// pack 2 f32 -> dword of 2 bf16 (RNE)
__device__ __forceinline__ unsigned pk2(float a, float b) {
    union { float f; unsigned u; } x, y; x.f = a; y.f = b;
    unsigned lo = (x.u + 0x7fff + ((x.u >> 16) & 1)) >> 16;
    unsigned hi = (y.u + 0x7fff + ((y.u >> 16) & 1)) >> 16;
    return lo | (hi << 16);
}
// half-up round f32 -> bf16 (hot loop; w in [0,1])
__device__ __forceinline__ short hup(float f) {
    union { float f; unsigned u; } v; v.f = f;
    return (short)((v.u + 0x8000) >> 16);
}

// ---------------------------------------------------------------------------
// adjb64[i][jw] = bitmask of adj[i][jw*64 .. jw*64+63]
// ---------------------------------------------------------------------------
__global__ __launch_bounds__(256)
void pack_adj(const int* __restrict__ adj, unsigned long long* __restrict__ adjb64)
{
    const int t    = threadIdx.x;
    const int gw   = blockIdx.x * 4 + (t >> 6);
    const int lane = t & 63;
    const int i  = gw >> 6;
    const int j0 = (gw & 63) * 64;
    const int a  = adj[(size_t)i * CNODES + j0 + lane];
    const unsigned long long m = __ballot(a != 0);
    if (lane == 0) adjb64[(size_t)i * 64 + (j0 >> 6)] = m;
}

// ---------------------------------------------------------------------------
// frag_T: src fp32 [K][N] row-major -> bf16 B-fragment order (weights).
// ---------------------------------------------------------------------------
__global__ __launch_bounds__(256)
void frag_T(const float* __restrict__ src, short* __restrict__ dst, int N, int K)
{
    __shared__ float tile[32][132];
    const int jc = blockIdx.x;   // K/32
    const int nq = blockIdx.y;   // N/128
    const int t  = threadIdx.x;
    const int KC = K >> 5;
#pragma unroll
    for (int it = 0; it < 16; it++) {
        const int e = it * 256 + t;
        const int j = e >> 7, n = e & 127;
        tile[j][n] = src[(size_t)(jc * 32 + j) * N + nq * 128 + n];
    }
    __syncthreads();
#pragma unroll
    for (int s = 0; s < 2; s++) {
        const int item = s * 256 + t;
        const int nbl = item >> 6, lane = item & 63;
        const int nr = lane & 15, kq = lane >> 4;
        short8 v;
#pragma unroll
        for (int jr = 0; jr < 8; jr++)
            v[jr] = f2bf(tile[kq * 8 + jr][nbl * 16 + nr]);
        *(short8*)&dst[((size_t)((nq * 8 + nbl) * KC + jc) * 64 + lane) * 8] = v;
    }
}

// ---------------------------------------------------------------------------
// frag_A: src fp32 [R][C] row-major -> bf16 A-fragment order (inputs).
// ---------------------------------------------------------------------------
__global__ __launch_bounds__(256)
void frag_A(const float* __restrict__ src, short* __restrict__ dst, int C)
{
    __shared__ float tile[16][132];
    const int rb = blockIdx.x, cq = blockIdx.y;
    const int t  = threadIdx.x;
    const int KC = C >> 5;
#pragma unroll
    for (int it = 0; it < 8; it++) {
        const int e = it * 256 + t;
        const int r = e >> 7, c = e & 127;
        tile[r][c] = src[(size_t)(rb * 16 + r) * C + cq * 128 + c];
    }
    __syncthreads();
    const int kcl = t >> 6, lane = t & 63;
    const int m = lane & 15, kq = lane >> 4;
    short8 v8;
#pragma unroll
    for (int j = 0; j < 8; j++) v8[j] = f2bf(tile[m][kcl * 32 + kq * 8 + j]);
    *(short8*)&dst[((size_t)(rb * KC + cq * 4 + kcl) * 64 + lane) * 8] = v8;
}

// ---------------------------------------------------------------------------
// gemm_hpre: hpre tile = A @ B^T (1-wave block, m-tile 32, n-tile 128 = one
// head). Epilogue: (a) write bf16 B-frags of hpre into hbTf via LDS bounce,
// (b) asrc/adst = hpre-tile . a_src/a_dst via in-register dots + butterfly.
// hpre is NEVER materialized row-major. grid (CNODES/32, NHEAD).
// ---------------------------------------------------------------------------
template <int KC>
__global__ __launch_bounds__(64)
void gemm_hpre(const short* __restrict__ Af, const short* __restrict__ Bf,
               const float* __restrict__ a_src, const float* __restrict__ a_dst,
               short* __restrict__ hbTf, float* __restrict__ asrc, float* __restrict__ adst)
{
    __shared__ __align__(16) short tileT[128][56];   // [col][row], 112B row-pitch (16B-mult)
    const int lane = threadIdx.x;
    const int mb0  = blockIdx.x * 2;
    const int nq   = blockIdx.y;       // head
    const int i0   = blockIdx.x * 32;

    f32x4 acc[2][8];
#pragma unroll
    for (int f = 0; f < 2; f++)
#pragma unroll
        for (int c = 0; c < 8; c++) acc[f][c] = (f32x4){0.f, 0.f, 0.f, 0.f};

    const short* ap0 = Af + (size_t)mb0 * KC * 512 + lane * 8;
    const short* ap1 = ap0 + (size_t)KC * 512;
    const short* bp  = Bf + (size_t)(nq * 8) * KC * 512 + lane * 8;

#pragma unroll 2
    for (int kc = 0; kc < KC; kc++) {
        short8 a0 = *(const short8*)(ap0 + (size_t)kc * 512);
        short8 a1 = *(const short8*)(ap1 + (size_t)kc * 512);
        short8 bf[8];
#pragma unroll
        for (int c = 0; c < 8; c++)
            bf[c] = *(const short8*)(bp + ((size_t)c * KC + kc) * 512);
#pragma unroll
        for (int c = 0; c < 8; c++) {
            acc[0][c] = __builtin_amdgcn_mfma_f32_16x16x32_bf16(a0, bf[c], acc[0][c], 0, 0, 0);
            acc[1][c] = __builtin_amdgcn_mfma_f32_16x16x32_bf16(a1, bf[c], acc[1][c], 0, 0, 0);
        }
    }

    const int col = lane & 15, q4 = lane >> 4;

    // (a) bf16 tile, column-major: tileT[local_col][local_row]
#pragma unroll
    for (int f = 0; f < 2; f++)
#pragma unroll
        for (int c = 0; c < 8; c++) {
            unsigned d0 = pk2(acc[f][c][0], acc[f][c][1]);
            unsigned d1 = pk2(acc[f][c][2], acc[f][c][3]);
            uint2 u; u.x = d0; u.y = d1;
            *(uint2*)&tileT[c * 16 + col][f * 16 + q4 * 4] = u;
        }
    __syncthreads();
    // read B-frags: element(lane=(kq,nr), jr) = tile[col=nbl*16+nr][row=kq*8+jr]
    {
        const int nr = lane & 15, kq = lane >> 4;
#pragma unroll
        for (int nbl = 0; nbl < 8; nbl++) {
            short8 v = *(const short8*)&tileT[nbl * 16 + nr][kq * 8];
            *(short8*)&hbTf[(((size_t)(nq * 8 + nbl) * (CNODES / 32) + blockIdx.x) * 64 + lane) * 8] = v;
        }
    }

    // (b) asrc/adst dots: per (f,r) row, sum over this lane's 8 col-chunks,
    // then butterfly over the 16 col-lanes.
    float ssrc[2][4] = {}, sdst[2][4] = {};
#pragma unroll
    for (int c = 0; c < 8; c++) {
        const float vs = a_src[nq * 128 + c * 16 + col];
        const float vd = a_dst[nq * 128 + c * 16 + col];
#pragma unroll
        for (int f = 0; f < 2; f++)
#pragma unroll
            for (int r = 0; r < 4; r++) {
                ssrc[f][r] += acc[f][c][r] * vs;
                sdst[f][r] += acc[f][c][r] * vd;
            }
    }
#pragma unroll
    for (int mask = 1; mask <= 8; mask <<= 1)
#pragma unroll
        for (int f = 0; f < 2; f++)
#pragma unroll
            for (int r = 0; r < 4; r++) {
                ssrc[f][r] += __shfl_xor(ssrc[f][r], mask);
                sdst[f][r] += __shfl_xor(sdst[f][r], mask);
            }
    if (col == 0) {
#pragma unroll
        for (int f = 0; f < 2; f++)
#pragma unroll
            for (int r = 0; r < 4; r++) {
                const int row = i0 + f * 16 + q4 * 4 + r;
                asrc[nq * CNODES + row] = ssrc[f][r];
                adst[nq * CNODES + row] = sdst[f][r];
            }
    }
}

// ---------------------------------------------------------------------------
// gemm_doc: doc_h tile = relu(A @ B^T + bias), written directly as bf16
// A-fragments (dhf) for the logits GEMM. 1-wave block, m-tile 16.
// grid (BDOCS/16, HID/128).
// ---------------------------------------------------------------------------
template <int KC>
__global__ __launch_bounds__(64)
void gemm_doc(const short* __restrict__ Af, const short* __restrict__ Bf,
              const float* __restrict__ bias, short* __restrict__ dhf)
{
    __shared__ __align__(16) short tile[16][128];   // row-major
    const int lane = threadIdx.x;
    const int mb = blockIdx.x;
    const int nq = blockIdx.y;

    f32x4 acc[8];
#pragma unroll
    for (int c = 0; c < 8; c++) acc[c] = (f32x4){0.f, 0.f, 0.f, 0.f};

    const short* ap = Af + (size_t)mb * KC * 512 + lane * 8;
    const short* bp = Bf + (size_t)(nq * 8) * KC * 512 + lane * 8;

#pragma unroll 2
    for (int kc = 0; kc < KC; kc++) {
        short8 a = *(const short8*)(ap + (size_t)kc * 512);
#pragma unroll
        for (int c = 0; c < 8; c++) {
            short8 bf = *(const short8*)(bp + ((size_t)c * KC + kc) * 512);
            acc[c] = __builtin_amdgcn_mfma_f32_16x16x32_bf16(a, bf, acc[c], 0, 0, 0);
        }
    }

    const int col = lane & 15, q4 = lane >> 4;
#pragma unroll
    for (int c = 0; c < 8; c++)
#pragma unroll
        for (int r = 0; r < 4; r++) {
            float v = fmaxf(acc[c][r] + bias[nq * 128 + c * 16 + col], 0.f);
            tile[q4 * 4 + r][c * 16 + col] = f2bf(v);
        }
    __syncthreads();
    const int m = lane & 15, kq = lane >> 4;
#pragma unroll
    for (int kcl = 0; kcl < 4; kcl++) {
        short8 v = *(const short8*)&tile[m][kcl * 32 + kq * 8];
        *(short8*)&dhf[(((size_t)mb * 16 + nq * 4 + kcl) * 64 + lane) * 8] = v;
    }
}

// ---------------------------------------------------------------------------
// gemm_frag: C[M][N] fp32 = A @ B^T from bf16 fragments (logits). 1-wave
// blocks, m-tile 32, n-tile 128. grid (M/32, N/128).
// ---------------------------------------------------------------------------
template <int KC>
__global__ __launch_bounds__(64)
void gemm_frag(const short* __restrict__ Af, const short* __restrict__ Bf,
               float* __restrict__ Cmat, int N)
{
    const int lane = threadIdx.x;
    const int mb0  = blockIdx.x * 2;
    const int nq   = blockIdx.y;

    f32x4 acc[2][8];
#pragma unroll
    for (int f = 0; f < 2; f++)
#pragma unroll
        for (int c = 0; c < 8; c++) acc[f][c] = (f32x4){0.f, 0.f, 0.f, 0.f};

    const short* ap0 = Af + (size_t)mb0 * KC * 512 + lane * 8;
    const short* ap1 = ap0 + (size_t)KC * 512;
    const short* bp  = Bf + (size_t)(nq * 8) * KC * 512 + lane * 8;

#pragma unroll 2
    for (int kc = 0; kc < KC; kc++) {
        short8 a0 = *(const short8*)(ap0 + (size_t)kc * 512);
        short8 a1 = *(const short8*)(ap1 + (size_t)kc * 512);
        short8 bf[8];
#pragma unroll
        for (int c = 0; c < 8; c++)
            bf[c] = *(const short8*)(bp + ((size_t)c * KC + kc) * 512);
#pragma unroll
        for (int c = 0; c < 8; c++) {
            acc[0][c] = __builtin_amdgcn_mfma_f32_16x16x32_bf16(a0, bf[c], acc[0][c], 0, 0, 0);
            acc[1][c] = __builtin_amdgcn_mfma_f32_16x16x32_bf16(a1, bf[c], acc[1][c], 0, 0, 0);
        }
    }

    const int col = lane & 15, q4 = lane >> 4;
#pragma unroll
    for (int f = 0; f < 2; f++)
#pragma unroll
        for (int c = 0; c < 8; c++)
#pragma unroll
            for (int r = 0; r < 4; r++) {
                const int row = (mb0 + f) * 16 + q4 * 4 + r;
                Cmat[(size_t)row * N + nq * 128 + c * 16 + col] = acc[f][c][r];
            }
}

// ---------------------------------------------------------------------------
// Mh[h] = max_j adst[h][j]  (unmasked upper bound — softmax shift-invariant)
// ---------------------------------------------------------------------------
__global__ __launch_bounds__(256)
void adst_max(const float* __restrict__ adst, float* __restrict__ Mh)
{
    const int h = blockIdx.x, t = threadIdx.x;
    __shared__ float red[256];
    float m = -1e30f;
    for (int j = t; j < CNODES; j += 256) m = fmaxf(m, adst[h * CNODES + j]);
    red[t] = m; __syncthreads();
    for (int s = 128; s >= 1; s >>= 1) {
        if (t < s) red[t] = fmaxf(red[t], red[t + s]);
        __syncthreads();
    }
    if (t == 0) Mh[h] = red[0];
}

// ---------------------------------------------------------------------------
// E1[h][j] = exp(adst-Mh), E2[h][j] = exp(0.2*(adst-Mh))  (both <= 1)
// ---------------------------------------------------------------------------
__global__ __launch_bounds__(256)
void exp_dst(const float* __restrict__ adst, const float* __restrict__ Mh,
             float* __restrict__ E1, float* __restrict__ E2)
{
    const int idx = blockIdx.x * 256 + threadIdx.x;
    const int h = idx >> 12;
    const float d = adst[idx] - Mh[h];
    E1[idx] = __expf(d);
    E2[idx] = __expf(0.2f * d);
}

// ---------------------------------------------------------------------------
// attn_pv: partial[ks][i][n] = sum_{j in slice} w_ij * V[j][n]. Barrier-free.
// Separable exp: w = (as+ad>0) ? A1_i*E1_j : A2_i*E2_j, sign test E1_j>T0_i.
// Row-sums l via ones-column MFMA. Block = 4 waves (wave = head), i-tile 32.
// ---------------------------------------------------------------------------
__global__ __launch_bounds__(256, 2)
void attn_pv(const short* __restrict__ hbTf,
             const unsigned int* __restrict__ adjb,
             const float* __restrict__ asrc,
             const float* __restrict__ E1, const float* __restrict__ E2,
             const float* __restrict__ Mh,
             float* __restrict__ part, float* __restrict__ lpart,
             int jper)
{
    const int t    = threadIdx.x;
    const int w    = t >> 6;        // head
    const int lane = t & 63;
    const int m    = lane & 15;
    const int kq   = lane >> 4;
    const int i0   = blockIdx.x * 32;
    const int ks   = blockIdx.y;
    const int js   = ks * jper;

    const float mh  = Mh[w];
    const float as0 = asrc[w * CNODES + i0 + m];
    const float as1 = asrc[w * CNODES + i0 + 16 + m];
    const float mr0 = lrelu(as0 + mh), mr1 = lrelu(as1 + mh);
    const float A10 = __expf(as0 + mh - mr0),        A11 = __expf(as1 + mh - mr1);
    const float A20 = __expf(0.2f * (as0 + mh) - mr0), A21 = __expf(0.2f * (as1 + mh) - mr1);
    const float T00 = __expf(-as0 - mh),             T01 = __expf(-as1 - mh);

    f32x4 acc[2][8], accO[2];
#pragma unroll
    for (int f = 0; f < 2; f++) {
        accO[f] = (f32x4){0.f, 0.f, 0.f, 0.f};
#pragma unroll
        for (int c = 0; c < 8; c++) acc[f][c] = (f32x4){0.f, 0.f, 0.f, 0.f};
    }
    short8 ones;
#pragma unroll
    for (int q = 0; q < 8; q++) ones[q] = (short)0x3F80;   // bf16 1.0

    const unsigned int* ar0 = adjb + (size_t)(i0 + m) * 128 + (js >> 5);
    const unsigned int* ar1 = adjb + (size_t)(i0 + 16 + m) * 128 + (js >> 5);
    const int nchunks = jper >> 5;

    for (int ch = 0; ch < nchunks; ch++) {
        const int j0 = js + ch * 32;
        const unsigned int aw0 = ar0[ch] >> (kq * 8);
        const unsigned int aw1 = ar1[ch] >> (kq * 8);
        const float4* p1 = (const float4*)(E1 + (size_t)w * CNODES + j0 + kq * 8);
        const float4* p2 = (const float4*)(E2 + (size_t)w * CNODES + j0 + kq * 8);
        const float4 x0 = p1[0], x1 = p1[1];
        const float4 y0 = p2[0], y1 = p2[1];
        const float e1v[8] = {x0.x, x0.y, x0.z, x0.w, x1.x, x1.y, x1.z, x1.w};
        const float e2v[8] = {y0.x, y0.y, y0.z, y0.w, y1.x, y1.y, y1.z, y1.w};

        short8 bf[8];
        const short* bbase = hbTf + (((size_t)(w * 8) * 128 + (j0 >> 5)) * 64 + lane) * 8;
#pragma unroll
        for (int c = 0; c < 8; c++)
            bf[c] = *(const short8*)(bbase + (size_t)c * 128 * 64 * 8);

        short8 a0, a1;
#pragma unroll
        for (int q = 0; q < 8; q++) {
            const float e1 = e1v[q], e2 = e2v[q];
            const bool c0 = e1 > T00, c1 = e1 > T01;
            float w0 = (c0 ? A10 : A20) * (c0 ? e1 : e2);
            float w1 = (c1 ? A11 : A21) * (c1 ? e1 : e2);
            w0 = ((aw0 >> q) & 1u) ? w0 : 0.f;
            w1 = ((aw1 >> q) & 1u) ? w1 : 0.f;
            a0[q] = hup(w0);
            a1[q] = hup(w1);
        }

#pragma unroll
        for (int c = 0; c < 8; c++) {
            acc[0][c] = __builtin_amdgcn_mfma_f32_16x16x32_bf16(a0, bf[c], acc[0][c], 0, 0, 0);
            acc[1][c] = __builtin_amdgcn_mfma_f32_16x16x32_bf16(a1, bf[c], acc[1][c], 0, 0, 0);
        }
        accO[0] = __builtin_amdgcn_mfma_f32_16x16x32_bf16(a0, ones, accO[0], 0, 0, 0);
        accO[1] = __builtin_amdgcn_mfma_f32_16x16x32_bf16(a1, ones, accO[1], 0, 0, 0);
    }

    const int col = lane & 15, q4 = lane >> 4;
    if (col == 0) {
#pragma unroll
        for (int f = 0; f < 2; f++)
#pragma unroll
            for (int r = 0; r < 4; r++)
                lpart[((size_t)ks * NHEAD + w) * CNODES + i0 + f * 16 + q4 * 4 + r] = accO[f][r];
    }

    float* pbase = part + (size_t)ks * CNODES * HID;
#pragma unroll
    for (int f = 0; f < 2; f++)
#pragma unroll
        for (int c = 0; c < 8; c++)
#pragma unroll
            for (int r = 0; r < 4; r++) {
                const int row = i0 + f * 16 + q4 * 4 + r;
                pbase[(size_t)row * HID + w * HDIM + c * 16 + col] = acc[f][c][r];
            }
}

// ---------------------------------------------------------------------------
// reduce_norm_frag: out = (sum_s part)/(sum_s lpart), optional ELU, written
// DIRECTLY as bf16 fragments (A-layout == B-layout index math; KC2 = HID/32).
// Wave handles (rb, kc): lane (m,kq) -> row rb*16+m, k = kc*32+kq*8..+8.
// ---------------------------------------------------------------------------
template <bool ELU>
__global__ __launch_bounds__(256)
void reduce_norm_frag(const float* __restrict__ part, const float* __restrict__ lpart,
                      short* __restrict__ dst, int KS)
{
    const int t = threadIdx.x;
    const int W = blockIdx.x * 4 + (t >> 6);
    const int lane = t & 63;
    const int rb = W >> 4, kc = W & 15;
    const int m = lane & 15, kq = lane >> 4;
    const int i = rb * 16 + m;
    const int n0 = kc * 32 + kq * 8;
    const int h = kc >> 2;

    float v[8] = {};
    float l = 0.f;
    for (int s = 0; s < KS; s++) {
        const float* p = part + (size_t)s * CNODES * HID + (size_t)i * HID + n0;
        const float4 a = ((const float4*)p)[0], b = ((const float4*)p)[1];
        v[0] += a.x; v[1] += a.y; v[2] += a.z; v[3] += a.w;
        v[4] += b.x; v[5] += b.y; v[6] += b.z; v[7] += b.w;
        l += lpart[((size_t)s * NHEAD + h) * CNODES + i];
    }
    const float inv = 1.0f / l;
    short8 o;
#pragma unroll
    for (int q = 0; q < 8; q++) {
        float x = v[q] * inv;
        if (ELU) x = x > 0.f ? x : (__expf(x) - 1.f);
        o[q] = f2bf(x);
    }
    *(short8*)&dst[((size_t)(rb * 16 + kc) * 64 + lane) * 8] = o;
}

// ---------------------------------------------------------------------------
extern "C" void kernel_launch(void* const* d_in, const int* in_sizes, int n_in,
                              void* d_out, int out_size, void* d_ws, size_t ws_size,
                              hipStream_t stream)
{
    const float* doc_x      = (const float*)d_in[0];
    const float* label_init = (const float*)d_in[1];
    const int*   adj        = (const int*)d_in[2];
    const float* W1         = (const float*)d_in[3];
    const float* a_src1     = (const float*)d_in[4];
    const float* a_dst1     = (const float*)d_in[5];
    const float* W2         = (const float*)d_in[6];
    const float* a_src2     = (const float*)d_in[7];
    const float* a_dst2     = (const float*)d_in[8];
    const float* Wd         = (const float*)d_in[9];
    const float* bd         = (const float*)d_in[10];
    float*       out        = (float*)d_out;

    char* wsb = (char*)d_ws;
    size_t off = 0;
    auto alloc = [&](size_t bytes) -> char* {
        char* p = wsb + off;
        off = (off + bytes + 255) & ~(size_t)255;
        return p;
    };

    float* asrc  = (float*)alloc(NHEAD * CNODES * 4);
    float* adst  = (float*)alloc(NHEAD * CNODES * 4);
    float* Mh    = (float*)alloc(256);
    float* E1    = (float*)alloc(NHEAD * CNODES * 4);
    float* E2    = (float*)alloc(NHEAD * CNODES * 4);
    float* lpart = (float*)alloc((size_t)8 * NHEAD * CNODES * 4);
    unsigned int* adjb = (unsigned int*)alloc((size_t)CNODES * 128 * 4);   // 2 MB
    short* hbTf  = (short*)alloc((size_t)CNODES * HID * 2);                // 4 MB
    short* Wdf   = (short*)alloc((size_t)INDIM * HID * 2);
    short* W1f   = (short*)alloc((size_t)INDIM * HID * 2);
    short* W2f   = (short*)alloc((size_t)HID * HID * 2);
    short* dxf   = (short*)alloc((size_t)BDOCS * INDIM * 2);
    short* Af_li = (short*)alloc((size_t)CNODES * INDIM * 2);              // 6 MB
    short* Af2   = (short*)alloc((size_t)CNODES * HID * 2);                // 4 MB
    short* lhf   = (short*)alloc((size_t)CNODES * HID * 2);                // 4 MB
    short* dhf   = (short*)alloc((size_t)BDOCS * HID * 2);                 // 1 MB
    float* part  = (float*)(wsb + off);

    int KS = 4;
    const size_t slice_bytes = (size_t)CNODES * HID * 4;
    while (KS > 1 && off + (size_t)KS * slice_bytes > ws_size) KS >>= 1;
    const int jper = CNODES / KS;

    const dim3 blk(256);

    // one-time transforms
    pack_adj<<<CNODES * CNODES / 64 / 4, blk, 0, stream>>>(adj, (unsigned long long*)adjb);
    frag_T<<<dim3(INDIM / 32, HID / 128), blk, 0, stream>>>(Wd, Wdf, HID, INDIM);
    frag_T<<<dim3(INDIM / 32, HID / 128), blk, 0, stream>>>(W1, W1f, HID, INDIM);
    frag_T<<<dim3(HID / 32, HID / 128), blk, 0, stream>>>(W2, W2f, HID, HID);
    frag_A<<<dim3(BDOCS / 16, INDIM / 128), blk, 0, stream>>>(doc_x, dxf, INDIM);
    frag_A<<<dim3(CNODES / 16, INDIM / 128), blk, 0, stream>>>(label_init, Af_li, INDIM);

    // doc_h = relu(doc_x @ Wd + bd) -> dhf A-frags (fused)
    gemm_doc<INDIM / 32><<<dim3(BDOCS / 16, HID / 128), 64, 0, stream>>>(dxf, Wdf, bd, dhf);

    // hpre1 = label_init @ W1 -> hbTf B-frags + asrc/adst (fused)
    gemm_hpre<INDIM / 32><<<dim3(CNODES / 32, NHEAD), 64, 0, stream>>>(
        Af_li, W1f, a_src1, a_dst1, hbTf, asrc, adst);

    // GAT layer 1
    adst_max<<<NHEAD, 256, 0, stream>>>(adst, Mh);
    exp_dst<<<NHEAD * CNODES / 256, blk, 0, stream>>>(adst, Mh, E1, E2);
    attn_pv<<<dim3(CNODES / 32, KS), blk, 0, stream>>>(hbTf, adjb, asrc, E1, E2, Mh, part, lpart, jper);
    reduce_norm_frag<true><<<CNODES * HID / 256 / 8, blk, 0, stream>>>(part, lpart, Af2, KS);

    // hpre2 = elu(gat1) @ W2 -> hbTf B-frags + asrc/adst (fused)
    gemm_hpre<HID / 32><<<dim3(CNODES / 32, NHEAD), 64, 0, stream>>>(
        Af2, W2f, a_src2, a_dst2, hbTf, asrc, adst);

    // GAT layer 2
    adst_max<<<NHEAD, 256, 0, stream>>>(adst, Mh);
    exp_dst<<<NHEAD * CNODES / 256, blk, 0, stream>>>(adst, Mh, E1, E2);
    attn_pv<<<dim3(CNODES / 32, KS), blk, 0, stream>>>(hbTf, adjb, asrc, E1, E2, Mh, part, lpart, jper);
    reduce_norm_frag<false><<<CNODES * HID / 256 / 8, blk, 0, stream>>>(part, lpart, lhf, KS);

    // logits = doc_h @ label_h^T -> out
    gemm_frag<HID / 32><<<dim3(BDOCS / 32, CNODES / 128), 64, 0, stream>>>(dhf, lhf, out, CNODES);
}

// Round 7
// 380.980 us; speedup vs baseline: 1.0803x; 1.0803x over previous
//
#include <hip/hip_runtime.h>
#include <hip/hip_bf16.h>
#include <math.h>

// Shapes are fixed by the problem instance.
#define BDOCS   1024
#define CNODES  4096
#define INDIM   768
#define HID     512
#define NHEAD   4
#define HDIM    128
#define NEG_SLOPE 0.2f

#define KSPLIT  8
#define JPER    (CNODES / KSPLIT)   // 512
#define NCH     (JPER / 32)         // 16

typedef __attribute__((ext_vector_type(8))) short short8;   // 8 bf16 (4 VGPRs)
typedef __attribute__((ext_vector_type(4))) float f32x4;    // MFMA C/D

__device__ __forceinline__ float lrelu(float x) { return x > 0.f ? x : NEG_SLOPE * x; }

// float -> bf16 bits, round-to-nearest-even
__device__ __forceinline__ short f2bf(float f) {
    union { float f; unsigned u; } v; v.f = f;
    unsigned r = (v.u + 0x7fff + ((v.u >> 16) & 1)) >> 16;
    return (short)r;
}
__device__ __forceinline__ float bf2f(short s) {
    union { float f; unsigned u; } v; v.u = ((unsigned)(unsigned short)s) << 16;
    return v.f;
}
// pack 2 f32 -> dword of 2 bf16 (RNE)
__device__ __forceinline__ unsigned pk2(float a, float b) {
    union { float f; unsigned u; } x, y; x.f = a; y.f = b;
    unsigned lo = (x.u + 0x7fff + ((x.u >> 16) & 1)) >> 16;
    unsigned hi = (y.u + 0x7fff + ((y.u >> 16) & 1)) >> 16;
    return lo | (hi << 16);
}
// half-up round f32 -> bf16 (hot loop; w in [0,1])
__device__ __forceinline__ short hup(float f) {
    union { float f; unsigned u; } v; v.f = f;
    return (short)((v.u + 0x8000) >> 16);
}

// ---------------------------------------------------------------------------
// adjb64[i][jw] = bitmask of adj[i][jw*64 .. jw*64+63]
// ---------------------------------------------------------------------------
__global__ __launch_bounds__(256)
void pack_adj(const int* __restrict__ adj, unsigned long long* __restrict__ adjb64)
{
    const int t    = threadIdx.x;
    const int gw   = blockIdx.x * 4 + (t >> 6);
    const int lane = t & 63;
    const int i  = gw >> 6;
    const int j0 = (gw & 63) * 64;
    const int a  = adj[(size_t)i * CNODES + j0 + lane];
    const unsigned long long m = __ballot(a != 0);
    if (lane == 0) adjb64[(size_t)i * 64 + (j0 >> 6)] = m;
}

// ---------------------------------------------------------------------------
// frag_T: src fp32 [K][N] row-major -> bf16 B-fragment order (weights).
// ---------------------------------------------------------------------------
__global__ __launch_bounds__(256)
void frag_T(const float* __restrict__ src, short* __restrict__ dst, int N, int K)
{
    __shared__ float tile[32][132];
    const int jc = blockIdx.x;   // K/32
    const int nq = blockIdx.y;   // N/128
    const int t  = threadIdx.x;
    const int KC = K >> 5;
#pragma unroll
    for (int it = 0; it < 16; it++) {
        const int e = it * 256 + t;
        const int j = e >> 7, n = e & 127;
        tile[j][n] = src[(size_t)(jc * 32 + j) * N + nq * 128 + n];
    }
    __syncthreads();
#pragma unroll
    for (int s = 0; s < 2; s++) {
        const int item = s * 256 + t;
        const int nbl = item >> 6, lane = item & 63;
        const int nr = lane & 15, kq = lane >> 4;
        short8 v;
#pragma unroll
        for (int jr = 0; jr < 8; jr++)
            v[jr] = f2bf(tile[kq * 8 + jr][nbl * 16 + nr]);
        *(short8*)&dst[((size_t)((nq * 8 + nbl) * KC + jc) * 64 + lane) * 8] = v;
    }
}

// ---------------------------------------------------------------------------
// frag_A: src fp32 [R][C] row-major -> bf16 A-fragment order (inputs).
// ---------------------------------------------------------------------------
__global__ __launch_bounds__(256)
void frag_A(const float* __restrict__ src, short* __restrict__ dst, int C)
{
    __shared__ float tile[16][132];
    const int rb = blockIdx.x, cq = blockIdx.y;
    const int t  = threadIdx.x;
    const int KC = C >> 5;
#pragma unroll
    for (int it = 0; it < 8; it++) {
        const int e = it * 256 + t;
        const int r = e >> 7, c = e & 127;
        tile[r][c] = src[(size_t)(rb * 16 + r) * C + cq * 128 + c];
    }
    __syncthreads();
    const int kcl = t >> 6, lane = t & 63;
    const int m = lane & 15, kq = lane >> 4;
    short8 v8;
#pragma unroll
    for (int j = 0; j < 8; j++) v8[j] = f2bf(tile[m][kcl * 32 + kq * 8 + j]);
    *(short8*)&dst[((size_t)(rb * KC + cq * 4 + kcl) * 64 + lane) * 8] = v8;
}

// ---------------------------------------------------------------------------
// gemm_hpre: hpre tile = A @ B^T. m-tile 16 (1 A-frag) -> grid (CNODES/16,
// NHEAD) = 1024 one-wave blocks (4 waves/CU). Epilogue: (a) write bf16
// HALF-B-frags of hpre into hbTf (blocks mb even/odd fill lanes kq 0-1/2-3
// of fragment jc=mb>>1), (b) asrc/adst row-dots + 16-lane butterfly.
// ---------------------------------------------------------------------------
template <int KC>
__global__ __launch_bounds__(64)
void gemm_hpre(const short* __restrict__ Af, const short* __restrict__ Bf,
               const float* __restrict__ a_src, const float* __restrict__ a_dst,
               short* __restrict__ hbTf, float* __restrict__ asrc, float* __restrict__ adst)
{
    __shared__ __align__(16) short tileT[128][24];   // [col][localrow], 48B pitch
    const int lane = threadIdx.x;
    const int mb   = blockIdx.x;       // 0..255
    const int nq   = blockIdx.y;       // head
    const int i0   = mb * 16;

    f32x4 acc[8];
#pragma unroll
    for (int c = 0; c < 8; c++) acc[c] = (f32x4){0.f, 0.f, 0.f, 0.f};

    const short* ap = Af + (size_t)mb * KC * 512 + lane * 8;
    const short* bp = Bf + (size_t)(nq * 8) * KC * 512 + lane * 8;

#pragma unroll 2
    for (int kc = 0; kc < KC; kc++) {
        short8 a = *(const short8*)(ap + (size_t)kc * 512);
#pragma unroll
        for (int c = 0; c < 8; c++) {
            short8 bf = *(const short8*)(bp + ((size_t)c * KC + kc) * 512);
            acc[c] = __builtin_amdgcn_mfma_f32_16x16x32_bf16(a, bf, acc[c], 0, 0, 0);
        }
    }

    const int col = lane & 15, q4 = lane >> 4;

    // (a) bf16 tile, column-major
#pragma unroll
    for (int c = 0; c < 8; c++) {
        uint2 u;
        u.x = pk2(acc[c][0], acc[c][1]);
        u.y = pk2(acc[c][2], acc[c][3]);
        *(uint2*)&tileT[c * 16 + col][q4 * 4] = u;
    }
    __syncthreads();
    {
        const int jc = mb >> 1, khalf = mb & 1;
        const int nr = lane & 15, kq = lane >> 4;
        if ((kq >> 1) == khalf) {
#pragma unroll
            for (int nbl = 0; nbl < 8; nbl++) {
                short8 v = *(const short8*)&tileT[nbl * 16 + nr][(kq & 1) * 8];
                *(short8*)&hbTf[(((size_t)(nq * 8 + nbl) * (CNODES / 32) + jc) * 64 + lane) * 8] = v;
            }
        }
    }

    // (b) asrc/adst dots
    float ssrc[4] = {}, sdst[4] = {};
#pragma unroll
    for (int c = 0; c < 8; c++) {
        const float vs = a_src[nq * 128 + c * 16 + col];
        const float vd = a_dst[nq * 128 + c * 16 + col];
#pragma unroll
        for (int r = 0; r < 4; r++) {
            ssrc[r] += acc[c][r] * vs;
            sdst[r] += acc[c][r] * vd;
        }
    }
#pragma unroll
    for (int mask = 1; mask <= 8; mask <<= 1)
#pragma unroll
        for (int r = 0; r < 4; r++) {
            ssrc[r] += __shfl_xor(ssrc[r], mask);
            sdst[r] += __shfl_xor(sdst[r], mask);
        }
    if (col == 0) {
#pragma unroll
        for (int r = 0; r < 4; r++) {
            const int row = i0 + q4 * 4 + r;
            asrc[nq * CNODES + row] = ssrc[r];
            adst[nq * CNODES + row] = sdst[r];
        }
    }
}

// ---------------------------------------------------------------------------
// gemm_doc: doc_h tile = relu(A @ B^T + bias) -> bf16 A-frags (dhf).
// m-tile 16, n-tile 64 (4 B-frags). grid (BDOCS/16, HID/64) = 512 blocks.
// ---------------------------------------------------------------------------
template <int KC>
__global__ __launch_bounds__(64)
void gemm_doc(const short* __restrict__ Af, const short* __restrict__ Bf,
              const float* __restrict__ bias, short* __restrict__ dhf)
{
    __shared__ __align__(16) short tile[16][64];
    const int lane = threadIdx.x;
    const int mb = blockIdx.x;
    const int ng = blockIdx.y;    // 64-col group

    f32x4 acc[4];
#pragma unroll
    for (int c = 0; c < 4; c++) acc[c] = (f32x4){0.f, 0.f, 0.f, 0.f};

    const short* ap = Af + (size_t)mb * KC * 512 + lane * 8;
    const short* bp = Bf + (size_t)(ng * 4) * KC * 512 + lane * 8;

#pragma unroll 2
    for (int kc = 0; kc < KC; kc++) {
        short8 a = *(const short8*)(ap + (size_t)kc * 512);
#pragma unroll
        for (int c = 0; c < 4; c++) {
            short8 bf = *(const short8*)(bp + ((size_t)c * KC + kc) * 512);
            acc[c] = __builtin_amdgcn_mfma_f32_16x16x32_bf16(a, bf, acc[c], 0, 0, 0);
        }
    }

    const int col = lane & 15, q4 = lane >> 4;
#pragma unroll
    for (int c = 0; c < 4; c++)
#pragma unroll
        for (int r = 0; r < 4; r++) {
            float v = fmaxf(acc[c][r] + bias[ng * 64 + c * 16 + col], 0.f);
            tile[q4 * 4 + r][c * 16 + col] = f2bf(v);
        }
    __syncthreads();
    const int m = lane & 15, kq = lane >> 4;
#pragma unroll
    for (int kcl = 0; kcl < 2; kcl++) {
        short8 v = *(const short8*)&tile[m][kcl * 32 + kq * 8];
        *(short8*)&dhf[(((size_t)mb * 16 + ng * 2 + kcl) * 64 + lane) * 8] = v;
    }
}

// ---------------------------------------------------------------------------
// gemm_frag: C[M][N] fp32 = A @ B^T from bf16 fragments (logits). 1-wave
// blocks, m-tile 32, n-tile 128. grid (M/32, N/128).
// ---------------------------------------------------------------------------
template <int KC>
__global__ __launch_bounds__(64)
void gemm_frag(const short* __restrict__ Af, const short* __restrict__ Bf,
               float* __restrict__ Cmat, int N)
{
    const int lane = threadIdx.x;
    const int mb0  = blockIdx.x * 2;
    const int nq   = blockIdx.y;

    f32x4 acc[2][8];
#pragma unroll
    for (int f = 0; f < 2; f++)
#pragma unroll
        for (int c = 0; c < 8; c++) acc[f][c] = (f32x4){0.f, 0.f, 0.f, 0.f};

    const short* ap0 = Af + (size_t)mb0 * KC * 512 + lane * 8;
    const short* ap1 = ap0 + (size_t)KC * 512;
    const short* bp  = Bf + (size_t)(nq * 8) * KC * 512 + lane * 8;

#pragma unroll 2
    for (int kc = 0; kc < KC; kc++) {
        short8 a0 = *(const short8*)(ap0 + (size_t)kc * 512);
        short8 a1 = *(const short8*)(ap1 + (size_t)kc * 512);
        short8 bf[8];
#pragma unroll
        for (int c = 0; c < 8; c++)
            bf[c] = *(const short8*)(bp + ((size_t)c * KC + kc) * 512);
#pragma unroll
        for (int c = 0; c < 8; c++) {
            acc[0][c] = __builtin_amdgcn_mfma_f32_16x16x32_bf16(a0, bf[c], acc[0][c], 0, 0, 0);
            acc[1][c] = __builtin_amdgcn_mfma_f32_16x16x32_bf16(a1, bf[c], acc[1][c], 0, 0, 0);
        }
    }

    const int col = lane & 15, q4 = lane >> 4;
#pragma unroll
    for (int f = 0; f < 2; f++)
#pragma unroll
        for (int c = 0; c < 8; c++)
#pragma unroll
            for (int r = 0; r < 4; r++) {
                const int row = (mb0 + f) * 16 + q4 * 4 + r;
                Cmat[(size_t)row * N + nq * 128 + c * 16 + col] = acc[f][c][r];
            }
}

// ---------------------------------------------------------------------------
// stats_exp: Mh[h] = max_j adst[h][j]; E1 = exp(adst-Mh); E2 = exp(0.2*(...)).
// One block per head, 1024 threads (4 j's each).
// ---------------------------------------------------------------------------
__global__ __launch_bounds__(1024)
void stats_exp(const float* __restrict__ adst, float* __restrict__ Mh,
               float* __restrict__ E1, float* __restrict__ E2)
{
    __shared__ float red[1024];
    __shared__ float s_mh;
    const int h = blockIdx.x, t = threadIdx.x;
    const float4 d4 = *(const float4*)(adst + (size_t)h * CNODES + t * 4);
    float m = fmaxf(fmaxf(d4.x, d4.y), fmaxf(d4.z, d4.w));
    red[t] = m; __syncthreads();
    for (int s = 512; s >= 1; s >>= 1) {
        if (t < s) red[t] = fmaxf(red[t], red[t + s]);
        __syncthreads();
    }
    if (t == 0) { s_mh = red[0]; Mh[h] = red[0]; }
    __syncthreads();
    const float mh = s_mh;
    float4 e1, e2;
    e1.x = __expf(d4.x - mh); e2.x = __expf(0.2f * (d4.x - mh));
    e1.y = __expf(d4.y - mh); e2.y = __expf(0.2f * (d4.y - mh));
    e1.z = __expf(d4.z - mh); e2.z = __expf(0.2f * (d4.z - mh));
    e1.w = __expf(d4.w - mh); e2.w = __expf(0.2f * (d4.w - mh));
    *(float4*)(E1 + (size_t)h * CNODES + t * 4) = e1;
    *(float4*)(E2 + (size_t)h * CNODES + t * 4) = e2;
}

// ---------------------------------------------------------------------------
// attn_pv: partial[ks][i][n] (bf16) = sum_{j in slice} w_ij * V[j][n].
// Barrier-free K-loop; separable exp; l via ones-column MFMA; bf16 partials
// written coalesced via LDS bounce. grid (CNODES/32, KSPLIT) = 1024 blocks.
// ---------------------------------------------------------------------------
__global__ __launch_bounds__(256, 3)
void attn_pv(const short* __restrict__ hbTf,
             const unsigned int* __restrict__ adjb,
             const float* __restrict__ asrc,
             const float* __restrict__ E1, const float* __restrict__ E2,
             const float* __restrict__ Mh,
             short* __restrict__ part, float* __restrict__ lpart)
{
    __shared__ __align__(16) short tileO[32][520];   // 33.3 KB, padded pitch
    const int t    = threadIdx.x;
    const int w    = t >> 6;        // head
    const int lane = t & 63;
    const int m    = lane & 15;
    const int kq   = lane >> 4;
    const int i0   = blockIdx.x * 32;
    const int ks   = blockIdx.y;
    const int js   = ks * JPER;

    const float mh  = Mh[w];
    const float as0 = asrc[w * CNODES + i0 + m];
    const float as1 = asrc[w * CNODES + i0 + 16 + m];
    const float mr0 = lrelu(as0 + mh), mr1 = lrelu(as1 + mh);
    const float A10 = __expf(as0 + mh - mr0),          A11 = __expf(as1 + mh - mr1);
    const float A20 = __expf(0.2f * (as0 + mh) - mr0), A21 = __expf(0.2f * (as1 + mh) - mr1);
    const float T00 = __expf(-as0 - mh),               T01 = __expf(-as1 - mh);

    f32x4 acc[2][8], accO[2];
#pragma unroll
    for (int f = 0; f < 2; f++) {
        accO[f] = (f32x4){0.f, 0.f, 0.f, 0.f};
#pragma unroll
        for (int c = 0; c < 8; c++) acc[f][c] = (f32x4){0.f, 0.f, 0.f, 0.f};
    }
    short8 ones;
#pragma unroll
    for (int q = 0; q < 8; q++) ones[q] = (short)0x3F80;   // bf16 1.0

    const unsigned int* ar0 = adjb + (size_t)(i0 + m) * 128 + ks * NCH;
    const unsigned int* ar1 = adjb + (size_t)(i0 + 16 + m) * 128 + ks * NCH;

#pragma unroll 2
    for (int ch = 0; ch < NCH; ch++) {
        const int j0 = js + ch * 32;
        const unsigned int aw0 = ar0[ch] >> (kq * 8);
        const unsigned int aw1 = ar1[ch] >> (kq * 8);
        const float4* p1 = (const float4*)(E1 + (size_t)w * CNODES + j0 + kq * 8);
        const float4* p2 = (const float4*)(E2 + (size_t)w * CNODES + j0 + kq * 8);
        const float4 x0 = p1[0], x1 = p1[1];
        const float4 y0 = p2[0], y1 = p2[1];
        const float e1v[8] = {x0.x, x0.y, x0.z, x0.w, x1.x, x1.y, x1.z, x1.w};
        const float e2v[8] = {y0.x, y0.y, y0.z, y0.w, y1.x, y1.y, y1.z, y1.w};

        short8 bf[8];
        const short* bbase = hbTf + (((size_t)(w * 8) * 128 + (j0 >> 5)) * 64 + lane) * 8;
#pragma unroll
        for (int c = 0; c < 8; c++)
            bf[c] = *(const short8*)(bbase + (size_t)c * 128 * 64 * 8);

        short8 a0, a1;
#pragma unroll
        for (int q = 0; q < 8; q++) {
            const float e1 = e1v[q], e2 = e2v[q];
            const bool c0 = e1 > T00, c1 = e1 > T01;
            float w0 = (c0 ? A10 : A20) * (c0 ? e1 : e2);
            float w1 = (c1 ? A11 : A21) * (c1 ? e1 : e2);
            w0 = ((aw0 >> q) & 1u) ? w0 : 0.f;
            w1 = ((aw1 >> q) & 1u) ? w1 : 0.f;
            a0[q] = hup(w0);
            a1[q] = hup(w1);
        }

#pragma unroll
        for (int c = 0; c < 8; c++) {
            acc[0][c] = __builtin_amdgcn_mfma_f32_16x16x32_bf16(a0, bf[c], acc[0][c], 0, 0, 0);
            acc[1][c] = __builtin_amdgcn_mfma_f32_16x16x32_bf16(a1, bf[c], acc[1][c], 0, 0, 0);
        }
        accO[0] = __builtin_amdgcn_mfma_f32_16x16x32_bf16(a0, ones, accO[0], 0, 0, 0);
        accO[1] = __builtin_amdgcn_mfma_f32_16x16x32_bf16(a1, ones, accO[1], 0, 0, 0);
    }

    const int col = lane & 15, q4 = lane >> 4;
    if (m == 0) {
#pragma unroll
        for (int f = 0; f < 2; f++)
#pragma unroll
            for (int r = 0; r < 4; r++)
                lpart[((size_t)ks * NHEAD + w) * CNODES + i0 + f * 16 + q4 * 4 + r] = accO[f][r];
    }

    // bf16 partials -> LDS tile (row-major 32 x 512), then coalesced store
#pragma unroll
    for (int f = 0; f < 2; f++)
#pragma unroll
        for (int c = 0; c < 8; c++)
#pragma unroll
            for (int r = 0; r < 4; r++)
                tileO[f * 16 + q4 * 4 + r][w * 128 + c * 16 + col] = f2bf(acc[f][c][r]);
    __syncthreads();
    short* pS = part + (size_t)ks * CNODES * HID;
#pragma unroll
    for (int it = 0; it < 8; it++) {
        const int u   = it * 256 + t;
        const int row = u >> 6, un = u & 63;
        uint4 v = *(const uint4*)&tileO[row][un * 8];
        *(uint4*)&pS[(size_t)(i0 + row) * HID + un * 8] = v;
    }
}

// ---------------------------------------------------------------------------
// reduce_norm_frag: out = (sum_s part)/(sum_s lpart), optional ELU, written
// directly as bf16 fragments. Wave = (rb, kc); lane (m,kq).
// ---------------------------------------------------------------------------
template <bool ELU>
__global__ __launch_bounds__(256)
void reduce_norm_frag(const short* __restrict__ part, const float* __restrict__ lpart,
                      short* __restrict__ dst)
{
    const int t = threadIdx.x;
    const int W = blockIdx.x * 4 + (t >> 6);
    const int lane = t & 63;
    const int rb = W >> 4, kc = W & 15;
    const int m = lane & 15, kq = lane >> 4;
    const int i = rb * 16 + m;
    const int n0 = kc * 32 + kq * 8;
    const int h = kc >> 2;

    float v[8] = {};
    float l = 0.f;
#pragma unroll
    for (int s = 0; s < KSPLIT; s++) {
        const uint4 raw = *(const uint4*)&part[(size_t)s * CNODES * HID + (size_t)i * HID + n0];
        const unsigned rr[4] = {raw.x, raw.y, raw.z, raw.w};
#pragma unroll
        for (int q = 0; q < 4; q++) {
            v[q * 2]     += bf2f((short)(rr[q] & 0xffff));
            v[q * 2 + 1] += bf2f((short)(rr[q] >> 16));
        }
        l += lpart[((size_t)s * NHEAD + h) * CNODES + i];
    }
    const float inv = 1.0f / l;
    short8 o;
#pragma unroll
    for (int q = 0; q < 8; q++) {
        float x = v[q] * inv;
        if (ELU) x = x > 0.f ? x : (__expf(x) - 1.f);
        o[q] = f2bf(x);
    }
    *(short8*)&dst[((size_t)(rb * 16 + kc) * 64 + lane) * 8] = o;
}

// ---------------------------------------------------------------------------
extern "C" void kernel_launch(void* const* d_in, const int* in_sizes, int n_in,
                              void* d_out, int out_size, void* d_ws, size_t ws_size,
                              hipStream_t stream)
{
    const float* doc_x      = (const float*)d_in[0];
    const float* label_init = (const float*)d_in[1];
    const int*   adj        = (const int*)d_in[2];
    const float* W1         = (const float*)d_in[3];
    const float* a_src1     = (const float*)d_in[4];
    const float* a_dst1     = (const float*)d_in[5];
    const float* W2         = (const float*)d_in[6];
    const float* a_src2     = (const float*)d_in[7];
    const float* a_dst2     = (const float*)d_in[8];
    const float* Wd         = (const float*)d_in[9];
    const float* bd         = (const float*)d_in[10];
    float*       out        = (float*)d_out;

    char* wsb = (char*)d_ws;
    size_t off = 0;
    auto alloc = [&](size_t bytes) -> char* {
        char* p = wsb + off;
        off = (off + bytes + 255) & ~(size_t)255;
        return p;
    };

    float* asrc  = (float*)alloc(NHEAD * CNODES * 4);
    float* adst  = (float*)alloc(NHEAD * CNODES * 4);
    float* Mh    = (float*)alloc(256);
    float* E1    = (float*)alloc(NHEAD * CNODES * 4);
    float* E2    = (float*)alloc(NHEAD * CNODES * 4);
    float* lpart = (float*)alloc((size_t)KSPLIT * NHEAD * CNODES * 4);
    unsigned int* adjb = (unsigned int*)alloc((size_t)CNODES * 128 * 4);   // 2 MB
    short* hbTf  = (short*)alloc((size_t)CNODES * HID * 2);                // 4 MB
    short* Wdf   = (short*)alloc((size_t)INDIM * HID * 2);
    short* W1f   = (short*)alloc((size_t)INDIM * HID * 2);
    short* W2f   = (short*)alloc((size_t)HID * HID * 2);
    short* dxf   = (short*)alloc((size_t)BDOCS * INDIM * 2);
    short* Af_li = (short*)alloc((size_t)CNODES * INDIM * 2);              // 6 MB
    short* Af2   = (short*)alloc((size_t)CNODES * HID * 2);                // 4 MB
    short* lhf   = (short*)alloc((size_t)CNODES * HID * 2);                // 4 MB
    short* dhf   = (short*)alloc((size_t)BDOCS * HID * 2);                 // 1 MB
    short* part  = (short*)alloc((size_t)KSPLIT * CNODES * HID * 2);       // 32 MB
    (void)ws_size;

    const dim3 blk(256);

    // one-time transforms
    pack_adj<<<CNODES * CNODES / 64 / 4, blk, 0, stream>>>(adj, (unsigned long long*)adjb);
    frag_T<<<dim3(INDIM / 32, HID / 128), blk, 0, stream>>>(Wd, Wdf, HID, INDIM);
    frag_T<<<dim3(INDIM / 32, HID / 128), blk, 0, stream>>>(W1, W1f, HID, INDIM);
    frag_T<<<dim3(HID / 32, HID / 128), blk, 0, stream>>>(W2, W2f, HID, HID);
    frag_A<<<dim3(BDOCS / 16, INDIM / 128), blk, 0, stream>>>(doc_x, dxf, INDIM);
    frag_A<<<dim3(CNODES / 16, INDIM / 128), blk, 0, stream>>>(label_init, Af_li, INDIM);

    // doc_h = relu(doc_x @ Wd + bd) -> dhf A-frags (fused)
    gemm_doc<INDIM / 32><<<dim3(BDOCS / 16, HID / 64), 64, 0, stream>>>(dxf, Wdf, bd, dhf);

    // hpre1 = label_init @ W1 -> hbTf B-frags + asrc/adst (fused)
    gemm_hpre<INDIM / 32><<<dim3(CNODES / 16, NHEAD), 64, 0, stream>>>(
        Af_li, W1f, a_src1, a_dst1, hbTf, asrc, adst);

    // GAT layer 1
    stats_exp<<<NHEAD, 1024, 0, stream>>>(adst, Mh, E1, E2);
    attn_pv<<<dim3(CNODES / 32, KSPLIT), blk, 0, stream>>>(hbTf, adjb, asrc, E1, E2, Mh, part, lpart);
    reduce_norm_frag<true><<<CNODES * HID / 256 / 8, blk, 0, stream>>>(part, lpart, Af2);

    // hpre2 = elu(gat1) @ W2 -> hbTf B-frags + asrc/adst (fused)
    gemm_hpre<HID / 32><<<dim3(CNODES / 16, NHEAD), 64, 0, stream>>>(
        Af2, W2f, a_src2, a_dst2, hbTf, asrc, adst);

    // GAT layer 2
    stats_exp<<<NHEAD, 1024, 0, stream>>>(adst, Mh, E1, E2);
    attn_pv<<<dim3(CNODES / 32, KSPLIT), blk, 0, stream>>>(hbTf, adjb, asrc, E1, E2, Mh, part, lpart);
    reduce_norm_frag<false><<<CNODES * HID / 256 / 8, blk, 0, stream>>>(part, lpart, lhf);

    // logits = doc_h @ label_h^T -> out
    gemm_frag<HID / 32><<<dim3(BDOCS / 32, CNODES / 128), 64, 0, stream>>>(dhf, lhf, out, CNODES);
}